// Round 4
// baseline (129.841 us; speedup 1.0000x reference)
//
#include <hip/hip_runtime.h>

// Tensor-train forward, B=4096 N=8 F=64 D=64 C=10.
// R5: R1 structure + explicit 4-deep A-prefetch register ring.
// R4 post-mortem: VGPR=56 proved the compiler never pipelined the A-loads
// (1 KB in flight/wave, L2 latency-bound, all pipes ~12%); setprio acted as
// a scheduling fence. R5: half8 A[4][2] ring, fully unrolled j-loop (static
// indices), prefetch j+3 issued before consuming stage j, no setprio.
// Base: 32 samples/block (128 blocks x 1024 thr), v-chain right-to-left,
// per step f16 MFMA GEMM W[(p,l),s]=A'[(p,l),r]*v[s,r], x[s,p]-weighted
// p-reduction fused in the D-fragment epilogue.

typedef _Float16 half8 __attribute__((ext_vector_type(8)));
typedef _Float16 half4 __attribute__((ext_vector_type(4)));
typedef _Float16 half2v __attribute__((ext_vector_type(2)));
typedef float f32x4 __attribute__((ext_vector_type(4)));

#define LAST_OFF   0          // 4 tiles * 2 kt * 64 lanes * 8 halves
#define MID_OFF    4096
#define MID_SZ     262144     // per mid core: 256 tiles * 2 * 64 * 8
#define FIRST_OFF  1576960    // 4096 + 6*262144
#define N_FRAGS    3208

// ---------- prologue: fp32 cores -> f16, MFMA-A-fragment swizzled ----------
__global__ __launch_bounds__(256) void tt_swz(
    const float* __restrict__ cf,   // core_first (10,64,64)  [c][p][r]
    const float* __restrict__ cm,   // cores_mid  (6,64,64,64)[ci][l][p][r]
    const float* __restrict__ cl,   // core_last  (64,64)     [l][p]
    _Float16* __restrict__ ws)
{
  int gid = blockIdx.x * 256 + threadIdx.x;
  if (gid >= N_FRAGS * 64) return;
  int lane = gid & 63, frag = gid >> 6;
  int quad = lane >> 4, m16 = lane & 15;
  half8 hv;
  _Float16* dst;
  if (frag < 8) {                       // core_last: rows l (4 tiles), k = p
    int t = frag >> 1, kt = frag & 1;
    int l = t * 16 + m16;
    const float* s = cl + l * 64 + kt * 32 + quad * 8;
#pragma unroll
    for (int j = 0; j < 8; ++j) hv[j] = (_Float16)s[j];
    dst = ws + LAST_OFF + (size_t)((t * 2 + kt) * 64 + lane) * 8;
  } else if (frag < 8 + 3072) {         // mid cores: rows (p,l), k = r
    int f2 = frag - 8;
    int ci = f2 >> 9, rem = f2 & 511;
    int t = rem >> 1, kt = rem & 1;
    int l = (t & 3) * 16 + m16, p = t >> 2;
    const float* s = cm + (((size_t)ci * 64 + l) * 64 + p) * 64 + kt * 32 + quad * 8;
#pragma unroll
    for (int j = 0; j < 8; ++j) hv[j] = (_Float16)s[j];
    dst = ws + MID_OFF + (size_t)ci * MID_SZ + (size_t)(rem * 64 + lane) * 8;
  } else {                              // core_first: rows c (pad 16), k = r
    int f2 = frag - 3080;
    int t = f2 >> 1, kt = f2 & 1;
    int c = m16, p = t;
    if (c < 10) {
      const float* s = cf + ((size_t)(c * 64 + p)) * 64 + kt * 32 + quad * 8;
#pragma unroll
      for (int j = 0; j < 8; ++j) hv[j] = (_Float16)s[j];
    } else {
#pragma unroll
      for (int j = 0; j < 8; ++j) hv[j] = (_Float16)0.f;
    }
    dst = ws + FIRST_OFF + (size_t)((t * 2 + kt) * 64 + lane) * 8;
  }
  *(half8*)dst = hv;
}

// ------------------- main chain: 128 blocks x 1024 threads -----------------
__global__ __launch_bounds__(1024) void tt_main(
    const float* __restrict__ x,        // (4096, 8, 64)
    const _Float16* __restrict__ ws,
    float* __restrict__ out)            // (4096, 10)
{
  __shared__ __align__(16) _Float16 Xs[512][33];     // [n*64+p][s] f16
  __shared__ __align__(16) _Float16 Vt[4][32][72];   // partials [part][s][l]
  __shared__ __align__(16) _Float16 Vc[32][72];      // combined  [s][r]
  const int tid = threadIdx.x;
  const int w = tid >> 6, lane = tid & 63;
  const int quad = lane >> 4, sl = lane & 15;
  const int blk = blockIdx.x;

  // ---- stage x (32 samples x 512 floats -> f16), zero spare Vt partials ----
  {
    const float* xb = x + (size_t)blk * 32 * 512;
    int s = tid >> 5, q = tid & 31;
#pragma unroll
    for (int k = 0; k < 4; ++k) {
      int f4 = q + 32 * k;
      float4 v = *(const float4*)(xb + (size_t)s * 512 + (size_t)f4 * 4);
      int row = f4 * 4;
      Xs[row + 0][s] = (_Float16)v.x;
      Xs[row + 1][s] = (_Float16)v.y;
      Xs[row + 2][s] = (_Float16)v.z;
      Xs[row + 3][s] = (_Float16)v.w;
    }
    _Float16* vz = &Vt[2][0][0];
    for (int idx = tid; idx < 2 * 32 * 72; idx += 1024) vz[idx] = (_Float16)0.f;
  }
  __syncthreads();

  // ---- GEMM1 (core_last): 16 wave-tasks = (st, kt, tt) ----
  {
    int st = w >> 3, kt = (w >> 2) & 1, tt = w & 3;
    half8 b;
#pragma unroll
    for (int j = 0; j < 8; ++j)
      b[j] = Xs[448 + kt * 32 + quad * 8 + j][st * 16 + sl];
    half8 a = *(const half8*)(ws + LAST_OFF + (size_t)((tt * 2 + kt) * 64 + lane) * 8);
    f32x4 d = {0.f, 0.f, 0.f, 0.f};
    d = __builtin_amdgcn_mfma_f32_16x16x32_f16(a, b, d, 0, 0, 0);
    half4 hv;
#pragma unroll
    for (int r = 0; r < 4; ++r) hv[r] = (_Float16)d[r];
    *(half4*)&Vt[kt][st * 16 + sl][tt * 16 + quad * 4] = hv;
  }
  __syncthreads();
  // combine partials -> Vc
  {
    int s = tid >> 5, rp = tid & 31;
    float r0 = 0.f, r1 = 0.f;
#pragma unroll
    for (int p = 0; p < 4; ++p) {
      half2v h = *(const half2v*)&Vt[p][s][rp * 2];
      r0 += (float)h[0]; r1 += (float)h[1];
    }
    half2v o; o[0] = (_Float16)r0; o[1] = (_Float16)r1;
    *(half2v*)&Vc[s][rp * 2] = o;
  }
  __syncthreads();

  const int g = w & 3, part = w >> 2;
  // ---- 6 middle steps (cores_mid[5] .. cores_mid[0]) ----
  for (int step = 0; step < 6; ++step) {
    int ci = 5 - step;
    // B-frags for both sample tiles & k-halves (single ds_read_b128 each)
    half8 b00 = *(const half8*)&Vc[sl][quad * 8];
    half8 b01 = *(const half8*)&Vc[sl][32 + quad * 8];
    half8 b10 = *(const half8*)&Vc[16 + sl][quad * 8];
    half8 b11 = *(const half8*)&Vc[16 + sl][32 + quad * 8];
    const _Float16* wl = ws + MID_OFF + (size_t)ci * MID_SZ
                       + (size_t)w * 1024 + (size_t)lane * 8;
    float c00 = 0.f, c01 = 0.f, c02 = 0.f, c03 = 0.f;
    float c10 = 0.f, c11 = 0.f, c12 = 0.f, c13 = 0.f;
    const int xrow = (ci + 1) * 64;
    // 4-deep A-prefetch ring; fully unrolled -> all indices static
    half8 A[4][2];
#pragma unroll
    for (int jj = 0; jj < 3; ++jj) {
      const _Float16* fp = wl + (size_t)jj * 16384;
      A[jj][0] = *(const half8*)fp;
      A[jj][1] = *(const half8*)(fp + 512);
    }
#pragma unroll
    for (int j = 0; j < 16; ++j) {
      const int js = j & 3;
      if (j + 3 < 16) {
        const _Float16* fp = wl + (size_t)(j + 3) * 16384;
        A[(j + 3) & 3][0] = *(const half8*)fp;
        A[(j + 3) & 3][1] = *(const half8*)(fp + 512);
      }
      int p = (j * 16 + w) >> 2;                // p = 4j + (w>>2)
      float xv0 = (float)Xs[xrow + p][sl];
      float xv1 = (float)Xs[xrow + p][16 + sl];
      f32x4 d0 = {0.f, 0.f, 0.f, 0.f}, d1 = {0.f, 0.f, 0.f, 0.f};
      d0 = __builtin_amdgcn_mfma_f32_16x16x32_f16(A[js][0], b00, d0, 0, 0, 0);
      d0 = __builtin_amdgcn_mfma_f32_16x16x32_f16(A[js][1], b01, d0, 0, 0, 0);
      d1 = __builtin_amdgcn_mfma_f32_16x16x32_f16(A[js][0], b10, d1, 0, 0, 0);
      d1 = __builtin_amdgcn_mfma_f32_16x16x32_f16(A[js][1], b11, d1, 0, 0, 0);
      c00 += xv0 * d0[0]; c01 += xv0 * d0[1]; c02 += xv0 * d0[2]; c03 += xv0 * d0[3];
      c10 += xv1 * d1[0]; c11 += xv1 * d1[1]; c12 += xv1 * d1[2]; c13 += xv1 * d1[3];
    }
    half4 h0, h1;
    h0[0] = (_Float16)c00; h0[1] = (_Float16)c01; h0[2] = (_Float16)c02; h0[3] = (_Float16)c03;
    h1[0] = (_Float16)c10; h1[1] = (_Float16)c11; h1[2] = (_Float16)c12; h1[3] = (_Float16)c13;
    *(half4*)&Vt[part][sl][g * 16 + quad * 4] = h0;
    *(half4*)&Vt[part][16 + sl][g * 16 + quad * 4] = h1;
    __syncthreads();
    {
      int s = tid >> 5, rp = tid & 31;
      float r0 = 0.f, r1 = 0.f;
#pragma unroll
      for (int p = 0; p < 4; ++p) {
        half2v h = *(const half2v*)&Vt[p][s][rp * 2];
        r0 += (float)h[0]; r1 += (float)h[1];
      }
      half2v o; o[0] = (_Float16)r0; o[1] = (_Float16)r1;
      *(half2v*)&Vc[s][rp * 2] = o;
    }
    __syncthreads();
  }

  // ---- final (core_first): 8 waves, 64 tiles (t = p); Red overlays Vt ----
  float* Red = (float*)&Vt[0][0][0];              // [8][10][32]
  if (w < 8) {
    half8 b00 = *(const half8*)&Vc[sl][quad * 8];
    half8 b01 = *(const half8*)&Vc[sl][32 + quad * 8];
    half8 b10 = *(const half8*)&Vc[16 + sl][quad * 8];
    half8 b11 = *(const half8*)&Vc[16 + sl][32 + quad * 8];
    float f00 = 0.f, f01 = 0.f, f02 = 0.f, f03 = 0.f;
    float f10 = 0.f, f11 = 0.f, f12 = 0.f, f13 = 0.f;
    half8 A[4][2];
#pragma unroll
    for (int jj = 0; jj < 3; ++jj) {
      const _Float16* fp = ws + FIRST_OFF + (size_t)(jj * 8 + w) * 1024 + (size_t)lane * 8;
      A[jj][0] = *(const half8*)fp;
      A[jj][1] = *(const half8*)(fp + 512);
    }
#pragma unroll
    for (int j = 0; j < 8; ++j) {
      const int js = j & 3;
      if (j + 3 < 8) {
        const _Float16* fp = ws + FIRST_OFF + (size_t)((j + 3) * 8 + w) * 1024 + (size_t)lane * 8;
        A[(j + 3) & 3][0] = *(const half8*)fp;
        A[(j + 3) & 3][1] = *(const half8*)(fp + 512);
      }
      int t = j * 8 + w;
      float xv0 = (float)Xs[t][sl];
      float xv1 = (float)Xs[t][16 + sl];
      f32x4 d0 = {0.f, 0.f, 0.f, 0.f}, d1 = {0.f, 0.f, 0.f, 0.f};
      d0 = __builtin_amdgcn_mfma_f32_16x16x32_f16(A[js][0], b00, d0, 0, 0, 0);
      d0 = __builtin_amdgcn_mfma_f32_16x16x32_f16(A[js][1], b01, d0, 0, 0, 0);
      d1 = __builtin_amdgcn_mfma_f32_16x16x32_f16(A[js][0], b10, d1, 0, 0, 0);
      d1 = __builtin_amdgcn_mfma_f32_16x16x32_f16(A[js][1], b11, d1, 0, 0, 0);
      f00 += xv0 * d0[0]; f01 += xv0 * d0[1]; f02 += xv0 * d0[2]; f03 += xv0 * d0[3];
      f10 += xv1 * d1[0]; f11 += xv1 * d1[1]; f12 += xv1 * d1[2]; f13 += xv1 * d1[3];
    }
    float a0[4] = {f00, f01, f02, f03};
    float a1[4] = {f10, f11, f12, f13};
#pragma unroll
    for (int r = 0; r < 4; ++r) {
      int c = quad * 4 + r;
      if (c < 10) {
        Red[(w * 10 + c) * 32 + sl] = a0[r];
        Red[(w * 10 + c) * 32 + 16 + sl] = a1[r];
      }
    }
  }
  __syncthreads();
  if (tid < 320) {
    int c = tid >> 5, s = tid & 31;
    float sum = 0.f;
#pragma unroll
    for (int ww = 0; ww < 8; ++ww) sum += Red[(ww * 10 + c) * 32 + s];
    out[((size_t)blk * 32 + s) * 10 + c] = sum;
  }
}

extern "C" void kernel_launch(void* const* d_in, const int* in_sizes, int n_in,
                              void* d_out, int out_size, void* d_ws, size_t ws_size,
                              hipStream_t stream) {
  const float* x  = (const float*)d_in[0];   // (4096,8,64)
  const float* cf = (const float*)d_in[1];   // (10,64,64)
  const float* cm = (const float*)d_in[2];   // (6,64,64,64)
  const float* cl = (const float*)d_in[3];   // (64,64)
  _Float16* ws = (_Float16*)d_ws;            // ~3.3 MB used
  float* out = (float*)d_out;
  tt_swz<<<dim3((N_FRAGS * 64 + 255) / 256), dim3(256), 0, stream>>>(cf, cm, cl, ws);
  tt_main<<<dim3(128), dim3(1024), 0, stream>>>(x, ws, out);
}

// Round 5
// 117.925 us; speedup vs baseline: 1.1011x; 1.1011x over previous
//
#include <hip/hip_runtime.h>

// Tensor-train forward, B=4096 N=8 F=64 D=64 C=10.
// R6: 64 samples/block (64 blocks x 1024 thr). Rationale: per-block A-core
// traffic (3.3 MB) is irreducible, so fatter blocks cut per-XCD L2 traffic
// 2x (8 blocks/XCD x 3.3 MB = 26 MB -> ~6us floor) and double compute per
// A-load (8 MFMAs/load-pair): per-wave L2 latency hidden by work.
// R5 lesson: half8 arrays spill to scratch (WRITE_SIZE 22MB) -> ping-pong
// uses NAMED registers only (PA0/PA1/QA0/QA1), fully static unroll.
// Chain: v right-to-left; per step f16 MFMA GEMM W[(p,l),s]=A'[(p,l),r]*v[s,r]
// with x[s,p]-weighted p-reduction fused in the D-fragment epilogue.

typedef _Float16 half8 __attribute__((ext_vector_type(8)));
typedef _Float16 half4 __attribute__((ext_vector_type(4)));
typedef float f32x4 __attribute__((ext_vector_type(4)));

#define LAST_OFF   0          // 4 tiles * 2 kt * 64 lanes * 8 halves
#define MID_OFF    4096
#define MID_SZ     262144     // per mid core: 256 tiles * 2 * 64 * 8
#define FIRST_OFF  1576960    // 4096 + 6*262144
#define N_FRAGS    3208

// ---------- prologue: fp32 cores -> f16, MFMA-A-fragment swizzled ----------
__global__ __launch_bounds__(256) void tt_swz(
    const float* __restrict__ cf,   // core_first (10,64,64)  [c][p][r]
    const float* __restrict__ cm,   // cores_mid  (6,64,64,64)[ci][l][p][r]
    const float* __restrict__ cl,   // core_last  (64,64)     [l][p]
    _Float16* __restrict__ ws)
{
  int gid = blockIdx.x * 256 + threadIdx.x;
  if (gid >= N_FRAGS * 64) return;
  int lane = gid & 63, frag = gid >> 6;
  int quad = lane >> 4, m16 = lane & 15;
  half8 hv;
  _Float16* dst;
  if (frag < 8) {                       // core_last: rows l (4 tiles), k = p
    int t = frag >> 1, kt = frag & 1;
    int l = t * 16 + m16;
    const float* s = cl + l * 64 + kt * 32 + quad * 8;
#pragma unroll
    for (int j = 0; j < 8; ++j) hv[j] = (_Float16)s[j];
    dst = ws + LAST_OFF + (size_t)((t * 2 + kt) * 64 + lane) * 8;
  } else if (frag < 8 + 3072) {         // mid cores: rows (p,l), k = r
    int f2 = frag - 8;
    int ci = f2 >> 9, rem = f2 & 511;
    int t = rem >> 1, kt = rem & 1;
    int l = (t & 3) * 16 + m16, p = t >> 2;
    const float* s = cm + (((size_t)ci * 64 + l) * 64 + p) * 64 + kt * 32 + quad * 8;
#pragma unroll
    for (int j = 0; j < 8; ++j) hv[j] = (_Float16)s[j];
    dst = ws + MID_OFF + (size_t)ci * MID_SZ + (size_t)(rem * 64 + lane) * 8;
  } else {                              // core_first: rows c (pad 16), k = r
    int f2 = frag - 3080;
    int t = f2 >> 1, kt = f2 & 1;
    int c = m16, p = t;
    if (c < 10) {
      const float* s = cf + ((size_t)(c * 64 + p)) * 64 + kt * 32 + quad * 8;
#pragma unroll
      for (int j = 0; j < 8; ++j) hv[j] = (_Float16)s[j];
    } else {
#pragma unroll
      for (int j = 0; j < 8; ++j) hv[j] = (_Float16)0.f;
    }
    dst = ws + FIRST_OFF + (size_t)((t * 2 + kt) * 64 + lane) * 8;
  }
  *(half8*)dst = hv;
}

// ------------------- main chain: 64 blocks x 1024 threads -----------------
__global__ __launch_bounds__(1024) void tt_main(
    const float* __restrict__ x,        // (4096, 8, 64)
    const _Float16* __restrict__ ws,
    float* __restrict__ out)            // (4096, 10)
{
  __shared__ __align__(16) _Float16 Xs[512][66];     // [n*64+p][s] f16, 64 samples
  __shared__ __align__(16) _Float16 Vt[4][64][72];   // partials [part][s][l]
  __shared__ __align__(16) _Float16 Vc[64][72];      // combined  [s][r]
  const int tid = threadIdx.x;
  const int w = tid >> 6, lane = tid & 63;
  const int quad = lane >> 4, sl = lane & 15;
  const int blk = blockIdx.x;
  const int g = w & 3, part = w >> 2;
  const int cs2 = tid >> 4, rp4 = (tid & 15) * 4;    // combine mapping

  // ---- stage x: 64 samples x 512 floats -> f16 [row][s] ----
  {
    const float* xb = x + (size_t)blk * 64 * 512;
    int s = tid >> 4, q = tid & 15;
#pragma unroll
    for (int k = 0; k < 8; ++k) {
      int f4 = q + 16 * k;
      float4 v = *(const float4*)(xb + (size_t)s * 512 + (size_t)f4 * 4);
      int row = f4 * 4;
      Xs[row + 0][s] = (_Float16)v.x;
      Xs[row + 1][s] = (_Float16)v.y;
      Xs[row + 2][s] = (_Float16)v.z;
      Xs[row + 3][s] = (_Float16)v.w;
    }
  }
  __syncthreads();

  // ---- GEMM1 (core_last): 32 tasks = (st,kt,tt), 16 waves x 2 ----
  {
    int sh = w >> 3, kt = (w >> 2) & 1, tt = w & 3;
    half8 a = *(const half8*)(ws + LAST_OFF + (size_t)((tt * 2 + kt) * 64 + lane) * 8);
#pragma unroll
    for (int st2 = 0; st2 < 2; ++st2) {
      int st = sh * 2 + st2;
      half8 b;
#pragma unroll
      for (int j = 0; j < 8; ++j)
        b[j] = Xs[448 + kt * 32 + quad * 8 + j][st * 16 + sl];
      f32x4 d = {0.f, 0.f, 0.f, 0.f};
      d = __builtin_amdgcn_mfma_f32_16x16x32_f16(a, b, d, 0, 0, 0);
      half4 hv;
#pragma unroll
      for (int r = 0; r < 4; ++r) hv[r] = (_Float16)d[r];
      *(half4*)&Vt[kt][st * 16 + sl][tt * 16 + quad * 4] = hv;
    }
  }
  __syncthreads();
  // combine parts 0,1 -> Vc
  {
    half4 t0 = *(const half4*)&Vt[0][cs2][rp4];
    half4 t1 = *(const half4*)&Vt[1][cs2][rp4];
    half4 o;
#pragma unroll
    for (int r = 0; r < 4; ++r) o[r] = (_Float16)((float)t0[r] + (float)t1[r]);
    *(half4*)&Vc[cs2][rp4] = o;
  }
  __syncthreads();

#define MID_LOAD(Xa, Xb, J) { \
    const _Float16* fp_ = wl + (size_t)(J) * 16384; \
    Xa = *(const half8*)fp_; \
    Xb = *(const half8*)(fp_ + 512); }

#define MID_MFMA(Xa, Xb, J) { \
    int p_ = (J) * 4 + part; \
    f32x4 d0 = {0.f,0.f,0.f,0.f}, d1 = d0, d2 = d0, d3 = d0; \
    d0 = __builtin_amdgcn_mfma_f32_16x16x32_f16(Xa, B00, d0, 0, 0, 0); \
    d0 = __builtin_amdgcn_mfma_f32_16x16x32_f16(Xb, B01, d0, 0, 0, 0); \
    d1 = __builtin_amdgcn_mfma_f32_16x16x32_f16(Xa, B10, d1, 0, 0, 0); \
    d1 = __builtin_amdgcn_mfma_f32_16x16x32_f16(Xb, B11, d1, 0, 0, 0); \
    d2 = __builtin_amdgcn_mfma_f32_16x16x32_f16(Xa, B20, d2, 0, 0, 0); \
    d2 = __builtin_amdgcn_mfma_f32_16x16x32_f16(Xb, B21, d2, 0, 0, 0); \
    d3 = __builtin_amdgcn_mfma_f32_16x16x32_f16(Xa, B30, d3, 0, 0, 0); \
    d3 = __builtin_amdgcn_mfma_f32_16x16x32_f16(Xb, B31, d3, 0, 0, 0); \
    float xv0 = (float)Xs[xrow + p_][sl]; \
    float xv1 = (float)Xs[xrow + p_][16 + sl]; \
    float xv2 = (float)Xs[xrow + p_][32 + sl]; \
    float xv3 = (float)Xs[xrow + p_][48 + sl]; \
    c0 += d0 * xv0; c1 += d1 * xv1; c2 += d2 * xv2; c3 += d3 * xv3; }

  // ---- 6 middle steps (cores_mid[5] .. cores_mid[0]) ----
  for (int step = 0; step < 6; ++step) {
    int ci = 5 - step;
    half8 B00 = *(const half8*)&Vc[sl][quad * 8];
    half8 B01 = *(const half8*)&Vc[sl][32 + quad * 8];
    half8 B10 = *(const half8*)&Vc[16 + sl][quad * 8];
    half8 B11 = *(const half8*)&Vc[16 + sl][32 + quad * 8];
    half8 B20 = *(const half8*)&Vc[32 + sl][quad * 8];
    half8 B21 = *(const half8*)&Vc[32 + sl][32 + quad * 8];
    half8 B30 = *(const half8*)&Vc[48 + sl][quad * 8];
    half8 B31 = *(const half8*)&Vc[48 + sl][32 + quad * 8];
    const _Float16* wl = ws + MID_OFF + (size_t)ci * MID_SZ
                       + (size_t)w * 1024 + (size_t)lane * 8;
    const int xrow = (ci + 1) * 64;
    f32x4 c0 = {0.f,0.f,0.f,0.f}, c1 = c0, c2 = c0, c3 = c0;
    half8 PA0, PA1, QA0, QA1;
    MID_LOAD(PA0, PA1, 0)
#pragma unroll
    for (int jj = 0; jj < 8; ++jj) {
      const int j0 = jj * 2, j1 = jj * 2 + 1;
      MID_LOAD(QA0, QA1, j1)
      MID_MFMA(PA0, PA1, j0)
      if (j1 + 1 < 16) MID_LOAD(PA0, PA1, j1 + 1)
      MID_MFMA(QA0, QA1, j1)
    }
    // write 4 sample-tile partials
    {
      half4 h;
#pragma unroll
      for (int r = 0; r < 4; ++r) h[r] = (_Float16)c0[r];
      *(half4*)&Vt[part][sl][g * 16 + quad * 4] = h;
#pragma unroll
      for (int r = 0; r < 4; ++r) h[r] = (_Float16)c1[r];
      *(half4*)&Vt[part][16 + sl][g * 16 + quad * 4] = h;
#pragma unroll
      for (int r = 0; r < 4; ++r) h[r] = (_Float16)c2[r];
      *(half4*)&Vt[part][32 + sl][g * 16 + quad * 4] = h;
#pragma unroll
      for (int r = 0; r < 4; ++r) h[r] = (_Float16)c3[r];
      *(half4*)&Vt[part][48 + sl][g * 16 + quad * 4] = h;
    }
    __syncthreads();
    // combine 4 parts -> Vc
    {
      half4 t0 = *(const half4*)&Vt[0][cs2][rp4];
      half4 t1 = *(const half4*)&Vt[1][cs2][rp4];
      half4 t2 = *(const half4*)&Vt[2][cs2][rp4];
      half4 t3 = *(const half4*)&Vt[3][cs2][rp4];
      half4 o;
#pragma unroll
      for (int r = 0; r < 4; ++r)
        o[r] = (_Float16)(((float)t0[r] + (float)t1[r]) + ((float)t2[r] + (float)t3[r]));
      *(half4*)&Vc[cs2][rp4] = o;
    }
    __syncthreads();
  }

  // ---- final (core_first): 8 waves, 64 tiles (t = p); Red overlays Vt ----
  float* Red = (float*)&Vt[0][0][0];              // [8][10][64] floats
  if (w < 8) {
    half8 B00 = *(const half8*)&Vc[sl][quad * 8];
    half8 B01 = *(const half8*)&Vc[sl][32 + quad * 8];
    half8 B10 = *(const half8*)&Vc[16 + sl][quad * 8];
    half8 B11 = *(const half8*)&Vc[16 + sl][32 + quad * 8];
    half8 B20 = *(const half8*)&Vc[32 + sl][quad * 8];
    half8 B21 = *(const half8*)&Vc[32 + sl][32 + quad * 8];
    half8 B30 = *(const half8*)&Vc[48 + sl][quad * 8];
    half8 B31 = *(const half8*)&Vc[48 + sl][32 + quad * 8];
    f32x4 c0 = {0.f,0.f,0.f,0.f}, c1 = c0, c2 = c0, c3 = c0;
#pragma unroll
    for (int j = 0; j < 8; ++j) {
      int t = j * 8 + w;                           // t == p
      const _Float16* fp = ws + FIRST_OFF + (size_t)t * 1024 + (size_t)lane * 8;
      half8 A0 = *(const half8*)fp;
      half8 A1 = *(const half8*)(fp + 512);
      f32x4 d0 = {0.f,0.f,0.f,0.f}, d1 = d0, d2 = d0, d3 = d0;
      d0 = __builtin_amdgcn_mfma_f32_16x16x32_f16(A0, B00, d0, 0, 0, 0);
      d0 = __builtin_amdgcn_mfma_f32_16x16x32_f16(A1, B01, d0, 0, 0, 0);
      d1 = __builtin_amdgcn_mfma_f32_16x16x32_f16(A0, B10, d1, 0, 0, 0);
      d1 = __builtin_amdgcn_mfma_f32_16x16x32_f16(A1, B11, d1, 0, 0, 0);
      d2 = __builtin_amdgcn_mfma_f32_16x16x32_f16(A0, B20, d2, 0, 0, 0);
      d2 = __builtin_amdgcn_mfma_f32_16x16x32_f16(A1, B21, d2, 0, 0, 0);
      d3 = __builtin_amdgcn_mfma_f32_16x16x32_f16(A0, B30, d3, 0, 0, 0);
      d3 = __builtin_amdgcn_mfma_f32_16x16x32_f16(A1, B31, d3, 0, 0, 0);
      float xv0 = (float)Xs[t][sl];
      float xv1 = (float)Xs[t][16 + sl];
      float xv2 = (float)Xs[t][32 + sl];
      float xv3 = (float)Xs[t][48 + sl];
      c0 += d0 * xv0; c1 += d1 * xv1; c2 += d2 * xv2; c3 += d3 * xv3;
    }
#pragma unroll
    for (int r = 0; r < 4; ++r) {
      int c = quad * 4 + r;
      if (c < 10) {
        Red[(w * 10 + c) * 64 + sl]      = c0[r];
        Red[(w * 10 + c) * 64 + 16 + sl] = c1[r];
        Red[(w * 10 + c) * 64 + 32 + sl] = c2[r];
        Red[(w * 10 + c) * 64 + 48 + sl] = c3[r];
      }
    }
  }
  __syncthreads();
  if (tid < 640) {
    int c = tid >> 6, s = tid & 63;
    float sum = 0.f;
#pragma unroll
    for (int ww = 0; ww < 8; ++ww) sum += Red[(ww * 10 + c) * 64 + s];
    out[((size_t)blk * 64 + s) * 10 + c] = sum;
  }
}

extern "C" void kernel_launch(void* const* d_in, const int* in_sizes, int n_in,
                              void* d_out, int out_size, void* d_ws, size_t ws_size,
                              hipStream_t stream) {
  const float* x  = (const float*)d_in[0];   // (4096,8,64)
  const float* cf = (const float*)d_in[1];   // (10,64,64)
  const float* cm = (const float*)d_in[2];   // (6,64,64,64)
  const float* cl = (const float*)d_in[3];   // (64,64)
  _Float16* ws = (_Float16*)d_ws;            // ~3.3 MB used
  float* out = (float*)d_out;
  tt_swz<<<dim3((N_FRAGS * 64 + 255) / 256), dim3(256), 0, stream>>>(cf, cm, cl, ws);
  tt_main<<<dim3(64), dim3(1024), 0, stream>>>(x, ws, out);
}

// Round 6
// 110.342 us; speedup vs baseline: 1.1767x; 1.0687x over previous
//
#include <hip/hip_runtime.h>

// Tensor-train forward, B=4096 N=8 F=64 D=64 C=10.
// R7: R1 structure (128 blocks x 1024 thr, 32 samples/block) + global_load_lds
// DMA ring for the mid-core A-stream. R4/R5/R6 lesson: hipcc will not deepen a
// register-load pipeline (VGPR proof R4; scratch spill R5; 2-deep only R6) ->
// per-wave latency-bound at ~31 B/cy/CU. Fix: per step, stream the 512 KB core
// as 16 x 32 KB chunks through a 3-slot LDS ring staged by
// __builtin_amdgcn_global_load_lds (width 16), consumed via ds_read_b128.
// One raw s_barrier + counted s_waitcnt vmcnt(2) per chunk (never 0 in the
// ring); all other barriers are lgkmcnt-only raw barriers so DMA prefetch
// survives step boundaries. sched_barrier(0) after barriers (rules #18/#19).
// Chain: v right-to-left; per step f16 MFMA GEMM W[(p,l),s]=A'[(p,l),r]*v[s,r]
// with x[s,p]-weighted p-reduction fused in the D-fragment epilogue.

typedef _Float16 half8 __attribute__((ext_vector_type(8)));
typedef _Float16 half4 __attribute__((ext_vector_type(4)));
typedef _Float16 half2v __attribute__((ext_vector_type(2)));
typedef float f32x4 __attribute__((ext_vector_type(4)));

#define LAST_OFF   0          // 4 tiles * 2 kt * 64 lanes * 8 halves
#define MID_OFF    4096
#define MID_SZ     262144     // per mid core: 256 tiles * 2 * 64 * 8
#define FIRST_OFF  1576960    // 4096 + 6*262144
#define N_FRAGS    3208
#define CH         16384      // ring chunk: 16384 halves = 32 KB

typedef __attribute__((address_space(3))) void lvoid_t;
typedef const __attribute__((address_space(1))) void gvoid_t;

#define LBAR() do { \
    asm volatile("s_waitcnt lgkmcnt(0)" ::: "memory"); \
    __builtin_amdgcn_s_barrier(); \
    __builtin_amdgcn_sched_barrier(0); } while (0)

// ---------- prologue: fp32 cores -> f16, MFMA-A-fragment swizzled ----------
__global__ __launch_bounds__(256) void tt_swz(
    const float* __restrict__ cf,   // core_first (10,64,64)  [c][p][r]
    const float* __restrict__ cm,   // cores_mid  (6,64,64,64)[ci][l][p][r]
    const float* __restrict__ cl,   // core_last  (64,64)     [l][p]
    _Float16* __restrict__ ws)
{
  int gid = blockIdx.x * 256 + threadIdx.x;
  if (gid >= N_FRAGS * 64) return;
  int lane = gid & 63, frag = gid >> 6;
  int quad = lane >> 4, m16 = lane & 15;
  half8 hv;
  _Float16* dst;
  if (frag < 8) {                       // core_last: rows l (4 tiles), k = p
    int t = frag >> 1, kt = frag & 1;
    int l = t * 16 + m16;
    const float* s = cl + l * 64 + kt * 32 + quad * 8;
#pragma unroll
    for (int j = 0; j < 8; ++j) hv[j] = (_Float16)s[j];
    dst = ws + LAST_OFF + (size_t)((t * 2 + kt) * 64 + lane) * 8;
  } else if (frag < 8 + 3072) {         // mid cores: rows (p,l), k = r
    int f2 = frag - 8;
    int ci = f2 >> 9, rem = f2 & 511;
    int t = rem >> 1, kt = rem & 1;
    int l = (t & 3) * 16 + m16, p = t >> 2;
    const float* s = cm + (((size_t)ci * 64 + l) * 64 + p) * 64 + kt * 32 + quad * 8;
#pragma unroll
    for (int j = 0; j < 8; ++j) hv[j] = (_Float16)s[j];
    dst = ws + MID_OFF + (size_t)ci * MID_SZ + (size_t)(rem * 64 + lane) * 8;
  } else {                              // core_first: rows c (pad 16), k = r
    int f2 = frag - 3080;
    int t = f2 >> 1, kt = f2 & 1;
    int c = m16, p = t;
    if (c < 10) {
      const float* s = cf + ((size_t)(c * 64 + p)) * 64 + kt * 32 + quad * 8;
#pragma unroll
      for (int j = 0; j < 8; ++j) hv[j] = (_Float16)s[j];
    } else {
#pragma unroll
      for (int j = 0; j < 8; ++j) hv[j] = (_Float16)0.f;
    }
    dst = ws + FIRST_OFF + (size_t)((t * 2 + kt) * 64 + lane) * 8;
  }
  *(half8*)dst = hv;
}

// ------------------- main chain: 128 blocks x 1024 threads -----------------
__global__ __launch_bounds__(1024) void tt_main(
    const float* __restrict__ x,        // (4096, 8, 64)
    const _Float16* __restrict__ ws,
    float* __restrict__ out)            // (4096, 10)
{
  __shared__ __align__(16) _Float16 Aring[3 * CH];   // 96 KB DMA ring
  __shared__ __align__(16) _Float16 Xs[512][33];     // [n*64+p][s] f16
  __shared__ __align__(16) _Float16 Vt[4][32][72];   // partials [part][s][l]
  __shared__ __align__(16) _Float16 Vc[32][72];      // combined  [s][r]
  const int tid = threadIdx.x;
  const int w = tid >> 6, lane = tid & 63;
  const int quad = lane >> 4, sl = lane & 15;
  const int blk = blockIdx.x;

  // stage chunk J (32 KB) of the mid-core stream into ring slot dstbase.
  // LDS image is a byte-linear copy of the swizzled global chunk.
  auto stage = [&](int J, _Float16* dstbase) {
    int stp = J >> 4, jj = J & 15;
    const _Float16* gb = ws + MID_OFF + (size_t)(5 - stp) * MID_SZ + (size_t)jj * CH;
    const _Float16* g0 = gb + (size_t)tid * 8;
    const _Float16* g1 = gb + (size_t)(tid + 1024) * 8;
    _Float16* l0 = dstbase + w * 512;          // wave-uniform base, lane*16 by HW
    _Float16* l1 = dstbase + 8192 + w * 512;
    __builtin_amdgcn_global_load_lds((gvoid_t*)g0, (lvoid_t*)l0, 16, 0, 0);
    __builtin_amdgcn_global_load_lds((gvoid_t*)g1, (lvoid_t*)l1, 16, 0, 0);
  };

  // ---- stage x (32 samples x 512 floats -> f16), zero spare Vt partials ----
  {
    const float* xb = x + (size_t)blk * 32 * 512;
    int s = tid >> 5, q = tid & 31;
#pragma unroll
    for (int k = 0; k < 4; ++k) {
      int f4 = q + 32 * k;
      float4 v = *(const float4*)(xb + (size_t)s * 512 + (size_t)f4 * 4);
      int row = f4 * 4;
      Xs[row + 0][s] = (_Float16)v.x;
      Xs[row + 1][s] = (_Float16)v.y;
      Xs[row + 2][s] = (_Float16)v.z;
      Xs[row + 3][s] = (_Float16)v.w;
    }
    _Float16* vz = &Vt[2][0][0];
    for (int idx = tid; idx < 2 * 32 * 72; idx += 1024) vz[idx] = (_Float16)0.f;
  }
  LBAR();

  // ---- GEMM1 (core_last): 16 wave-tasks = (st, kt, tt) ----
  {
    int st = w >> 3, kt = (w >> 2) & 1, tt = w & 3;
    half8 b;
#pragma unroll
    for (int j = 0; j < 8; ++j)
      b[j] = Xs[448 + kt * 32 + quad * 8 + j][st * 16 + sl];
    half8 a = *(const half8*)(ws + LAST_OFF + (size_t)((tt * 2 + kt) * 64 + lane) * 8);
    f32x4 d = {0.f, 0.f, 0.f, 0.f};
    d = __builtin_amdgcn_mfma_f32_16x16x32_f16(a, b, d, 0, 0, 0);
    half4 hv;
#pragma unroll
    for (int r = 0; r < 4; ++r) hv[r] = (_Float16)d[r];
    *(half4*)&Vt[kt][st * 16 + sl][tt * 16 + quad * 4] = hv;
  }
  // prologue DMA: chunks 0,1 -> slots 0,1 (overlaps combine below)
  stage(0, Aring);
  stage(1, Aring + CH);
  LBAR();
  // combine partials -> Vc
  {
    int s = tid >> 5, rp = tid & 31;
    float r0 = 0.f, r1 = 0.f;
#pragma unroll
    for (int p = 0; p < 4; ++p) {
      half2v h = *(const half2v*)&Vt[p][s][rp * 2];
      r0 += (float)h[0]; r1 += (float)h[1];
    }
    half2v o; o[0] = (_Float16)r0; o[1] = (_Float16)r1;
    *(half2v*)&Vc[s][rp * 2] = o;
  }
  LBAR();

  const int g = w & 3, part = w >> 2;
  _Float16* pc = Aring;            // consume slot (chunk J)
  _Float16* pn = Aring + CH;       // next slot   (chunk J+1, in flight)
  _Float16* ps = Aring + 2 * CH;   // stage slot  (chunk J+2 target)

  // ---- 6 middle steps (cores_mid[5] .. cores_mid[0]) ----
  for (int step = 0; step < 6; ++step) {
    int ci = 5 - step;
    half8 b00 = *(const half8*)&Vc[sl][quad * 8];
    half8 b01 = *(const half8*)&Vc[sl][32 + quad * 8];
    half8 b10 = *(const half8*)&Vc[16 + sl][quad * 8];
    half8 b11 = *(const half8*)&Vc[16 + sl][32 + quad * 8];
    float c00 = 0.f, c01 = 0.f, c02 = 0.f, c03 = 0.f;
    float c10 = 0.f, c11 = 0.f, c12 = 0.f, c13 = 0.f;
    const int xrow = (ci + 1) * 64;
#pragma unroll
    for (int j = 0; j < 16; ++j) {
      const int J = step * 16 + j;
      // chunk J's DMA (issued 2 iterations ago) must be complete; keep the
      // following chunk in flight (counted vmcnt, never 0 until the tail).
      if (J <= 94) asm volatile("s_waitcnt vmcnt(2)" ::: "memory");
      else         asm volatile("s_waitcnt vmcnt(0)" ::: "memory");
      __builtin_amdgcn_s_barrier();
      __builtin_amdgcn_sched_barrier(0);
      const _Float16* ap = pc + w * 1024 + lane * 8;
      half8 A0 = *(const half8*)ap;          // ds_read_b128
      half8 A1 = *(const half8*)(ap + 512);
      if (J + 2 < 96) stage(J + 2, ps);      // refill slot freed at J-1
      int p = (j * 16 + w) >> 2;             // p = 4j + (w>>2)
      float xv0 = (float)Xs[xrow + p][sl];
      float xv1 = (float)Xs[xrow + p][16 + sl];
      f32x4 d0 = {0.f, 0.f, 0.f, 0.f}, d1 = {0.f, 0.f, 0.f, 0.f};
      d0 = __builtin_amdgcn_mfma_f32_16x16x32_f16(A0, b00, d0, 0, 0, 0);
      d0 = __builtin_amdgcn_mfma_f32_16x16x32_f16(A1, b01, d0, 0, 0, 0);
      d1 = __builtin_amdgcn_mfma_f32_16x16x32_f16(A0, b10, d1, 0, 0, 0);
      d1 = __builtin_amdgcn_mfma_f32_16x16x32_f16(A1, b11, d1, 0, 0, 0);
      c00 += xv0 * d0[0]; c01 += xv0 * d0[1]; c02 += xv0 * d0[2]; c03 += xv0 * d0[3];
      c10 += xv1 * d1[0]; c11 += xv1 * d1[1]; c12 += xv1 * d1[2]; c13 += xv1 * d1[3];
      _Float16* t = pc; pc = pn; pn = ps; ps = t;   // rotate ring
    }
    half4 h0, h1;
    h0[0] = (_Float16)c00; h0[1] = (_Float16)c01; h0[2] = (_Float16)c02; h0[3] = (_Float16)c03;
    h1[0] = (_Float16)c10; h1[1] = (_Float16)c11; h1[2] = (_Float16)c12; h1[3] = (_Float16)c13;
    *(half4*)&Vt[part][sl][g * 16 + quad * 4] = h0;
    *(half4*)&Vt[part][16 + sl][g * 16 + quad * 4] = h1;
    LBAR();
    {
      int s = tid >> 5, rp = tid & 31;
      float r0 = 0.f, r1 = 0.f;
#pragma unroll
      for (int p = 0; p < 4; ++p) {
        half2v h = *(const half2v*)&Vt[p][s][rp * 2];
        r0 += (float)h[0]; r1 += (float)h[1];
      }
      half2v o; o[0] = (_Float16)r0; o[1] = (_Float16)r1;
      *(half2v*)&Vc[s][rp * 2] = o;
    }
    LBAR();
  }

  // ---- final (core_first): 8 waves, 64 tiles (t = p); Red overlays Vt ----
  float* Red = (float*)&Vt[0][0][0];              // [8][10][32]
  if (w < 8) {
    half8 b00 = *(const half8*)&Vc[sl][quad * 8];
    half8 b01 = *(const half8*)&Vc[sl][32 + quad * 8];
    half8 b10 = *(const half8*)&Vc[16 + sl][quad * 8];
    half8 b11 = *(const half8*)&Vc[16 + sl][32 + quad * 8];
    float f00 = 0.f, f01 = 0.f, f02 = 0.f, f03 = 0.f;
    float f10 = 0.f, f11 = 0.f, f12 = 0.f, f13 = 0.f;
#pragma unroll
    for (int j = 0; j < 8; ++j) {
      int t = j * 8 + w;
      const _Float16* fp = ws + FIRST_OFF + (size_t)t * 1024 + (size_t)lane * 8;
      half8 A0 = *(const half8*)fp;
      half8 A1 = *(const half8*)(fp + 512);
      float xv0 = (float)Xs[t][sl];
      float xv1 = (float)Xs[t][16 + sl];
      f32x4 d0 = {0.f, 0.f, 0.f, 0.f}, d1 = {0.f, 0.f, 0.f, 0.f};
      d0 = __builtin_amdgcn_mfma_f32_16x16x32_f16(A0, b00, d0, 0, 0, 0);
      d0 = __builtin_amdgcn_mfma_f32_16x16x32_f16(A1, b01, d0, 0, 0, 0);
      d1 = __builtin_amdgcn_mfma_f32_16x16x32_f16(A0, b10, d1, 0, 0, 0);
      d1 = __builtin_amdgcn_mfma_f32_16x16x32_f16(A1, b11, d1, 0, 0, 0);
      f00 += xv0 * d0[0]; f01 += xv0 * d0[1]; f02 += xv0 * d0[2]; f03 += xv0 * d0[3];
      f10 += xv1 * d1[0]; f11 += xv1 * d1[1]; f12 += xv1 * d1[2]; f13 += xv1 * d1[3];
    }
    float a0[4] = {f00, f01, f02, f03};
    float a1[4] = {f10, f11, f12, f13};
#pragma unroll
    for (int r = 0; r < 4; ++r) {
      int c = quad * 4 + r;
      if (c < 10) {
        Red[(w * 10 + c) * 32 + sl] = a0[r];
        Red[(w * 10 + c) * 32 + 16 + sl] = a1[r];
      }
    }
  }
  LBAR();
  if (tid < 320) {
    int c = tid >> 5, s = tid & 31;
    float sum = 0.f;
#pragma unroll
    for (int ww = 0; ww < 8; ++ww) sum += Red[(ww * 10 + c) * 32 + s];
    out[((size_t)blk * 32 + s) * 10 + c] = sum;
  }
}

extern "C" void kernel_launch(void* const* d_in, const int* in_sizes, int n_in,
                              void* d_out, int out_size, void* d_ws, size_t ws_size,
                              hipStream_t stream) {
  const float* x  = (const float*)d_in[0];   // (4096,8,64)
  const float* cf = (const float*)d_in[1];   // (10,64,64)
  const float* cm = (const float*)d_in[2];   // (6,64,64,64)
  const float* cl = (const float*)d_in[3];   // (64,64)
  _Float16* ws = (_Float16*)d_ws;            // ~3.3 MB used
  float* out = (float*)d_out;
  tt_swz<<<dim3((N_FRAGS * 64 + 255) / 256), dim3(256), 0, stream>>>(cf, cm, cl, ws);
  tt_main<<<dim3(128), dim3(1024), 0, stream>>>(x, ws, out);
}